// Round 1
// baseline (832.293 us; speedup 1.0000x reference)
//
#include <hip/hip_runtime.h>

#define FDIM 16

struct PlanePtrs { const float* p[12]; };

// PAIRS = (0,1),(0,2),(1,2),(0,3),(1,3),(2,3)
// i-selectors packed: 0,0,1,0,1,2 -> 2320 ; j-selectors: 1,2,2,3,3,3 -> 4073
__device__ __forceinline__ void plane_dims(int k, int& H, int& W, int& toff,
                                           int& isel, int& jsel) {
    int pi  = (k >= 6) ? (k - 6) : k;
    int lvl = (k >= 6) ? 1 : 0;
    isel = (2320 >> (2 * pi)) & 3;
    jsel = (4073 >> (2 * pi)) & 3;
    // plane shape is (F, res[i], res[j]); gy=c[j] indexes H=res[i], gx=c[i] indexes W=res[j]
    H = ((isel == 3) ? 150 : 128) >> lvl;
    W = ((jsel == 3) ? 150 : 128) >> lvl;
    // cumulative texel offsets: 3x16384, 3x19200, 3x4096, 3x4800
    if (k < 6) {
        toff = (k < 3) ? k * 16384 : 49152 + (k - 3) * 19200;
    } else {
        int kk = k - 6;
        toff = 106752 + ((kk < 3) ? kk * 4096 : 12288 + (kk - 3) * 4800);
    }
}

// (F,H,W) -> (H,W,F) so the 16 features of a texel are contiguous (4 x float4)
__global__ void __launch_bounds__(256) hex_transpose(PlanePtrs ptrs,
                                                     float4* __restrict__ ws4) {
    int k = blockIdx.y;
    int H, W, toff, isel, jsel;
    plane_dims(k, H, W, toff, isel, jsel);
    int HW = H * W;
    int t = blockIdx.x * 256 + threadIdx.x;
    if (t >= HW) return;
    const float* __restrict__ src = ptrs.p[k];
    float v[FDIM];
#pragma unroll
    for (int f = 0; f < FDIM; ++f) v[f] = src[f * HW + t];   // coalesced per f
    float4* dst = ws4 + (size_t)(toff + t) * 4;
#pragma unroll
    for (int j = 0; j < 4; ++j)
        dst[j] = make_float4(v[4 * j], v[4 * j + 1], v[4 * j + 2], v[4 * j + 3]);
}

// One thread = one float4 of output. idx = p*48 + k*4 + q  (same as out4 index)
__global__ void __launch_bounds__(256) hex_sample(const float4* __restrict__ coords,
                                                  const float4* __restrict__ ws4,
                                                  float4* __restrict__ out4,
                                                  int total) {
    int idx = blockIdx.x * 256 + threadIdx.x;
    if (idx >= total) return;
    int q = idx & 3;
    int r = idx >> 2;          // p*12 + k
    int k = r % 12;
    int p = r / 12;

    float4 c = coords[p];

    int H, W, toff, isel, jsel;
    plane_dims(k, H, W, toff, isel, jsel);

    // isel in {0,1,2}, jsel in {1,2,3}
    float gx = (isel == 0) ? c.x : (isel == 1) ? c.y : c.z;
    float gy = (jsel == 1) ? c.y : (jsel == 2) ? c.z : c.w;

    // align_corners=True + border padding: clip BEFORE floor
    float fx = (gx + 1.0f) * 0.5f * (float)(W - 1);
    fx = fminf(fmaxf(fx, 0.0f), (float)(W - 1));
    float fy = (gy + 1.0f) * 0.5f * (float)(H - 1);
    fy = fminf(fmaxf(fy, 0.0f), (float)(H - 1));

    float x0f = floorf(fx), y0f = floorf(fy);
    int x0 = (int)x0f, y0 = (int)y0f;
    int x1 = min(x0 + 1, W - 1);
    int y1 = min(y0 + 1, H - 1);
    float wx = fx - x0f, wy = fy - y0f;

    const float4* base = ws4 + (size_t)toff * 4 + q;   // q selects the feature quad
    float4 v00 = base[(y0 * W + x0) * 4];
    float4 v01 = base[(y0 * W + x1) * 4];
    float4 v10 = base[(y1 * W + x0) * 4];
    float4 v11 = base[(y1 * W + x1) * 4];

    float w00 = (1.0f - wx) * (1.0f - wy);
    float w01 = wx * (1.0f - wy);
    float w10 = (1.0f - wx) * wy;
    float w11 = wx * wy;

    float4 o;
    o.x = v00.x * w00 + v01.x * w01 + v10.x * w10 + v11.x * w11;
    o.y = v00.y * w00 + v01.y * w01 + v10.y * w10 + v11.y * w11;
    o.z = v00.z * w00 + v01.z * w01 + v10.z * w10 + v11.z * w11;
    o.w = v00.w * w00 + v01.w * w01 + v10.w * w10 + v11.w * w11;

    out4[idx] = o;   // perfectly coalesced: idx is the global thread id
}

extern "C" void kernel_launch(void* const* d_in, const int* in_sizes, int n_in,
                              void* d_out, int out_size, void* d_ws, size_t ws_size,
                              hipStream_t stream) {
    const float4* coords = (const float4*)d_in[0];
    PlanePtrs pp;
    for (int i = 0; i < 12; ++i) pp.p[i] = (const float*)d_in[1 + i];
    float4* ws4  = (float4*)d_ws;    // needs 8,540,160 bytes
    float4* out4 = (float4*)d_out;

    int points = in_sizes[0] / 4;    // 800,000

    // transpose: max HW = 19200 -> 75 blocks; y = plane index
    dim3 tgrid(75, 12);
    hex_transpose<<<tgrid, 256, 0, stream>>>(pp, ws4);

    int total  = points * 48;        // 38.4M float4 outputs
    int blocks = (total + 255) / 256;
    hex_sample<<<blocks, 256, 0, stream>>>(coords, ws4, out4, total);
}